// Round 22
// baseline (1358.296 us; speedup 1.0000x reference)
//
#include <hip/hip_runtime.h>

typedef unsigned short u16;
typedef unsigned int   u32;
typedef __attribute__((ext_vector_type(8))) short bf16x8;
typedef __attribute__((ext_vector_type(4))) float f32x4;

#define NB 64
#define TT 256
#define FF 1024
#define HH 1024
#define KK 2048
#define GG 4096
#define NBLK 256

// ws layout in u16 units
#define WPACK_SZ  (KK*GG)                    // 8388608 u16 = 16 MB
#define XPACK_SZ  ((size_t)NB*TT*FF)         // 16777216 u16 = 32 MB
#define HPACK_SZ  (2*4*32*64*8)              // 131072 u16 = 256 KB (double buffer)
#define FLAGS_SZ  (4*64*4)                   // u32: 4 rt-groups x 64 flags, 16B stride

__device__ __forceinline__ u16 f2bf(float f) {
  u32 u = __float_as_uint(f);
  u32 r = (u + 0x7FFFu + ((u >> 16) & 1u)) >> 16;
  return (u16)r;
}

// Pack W [K=2048][G=4096] fp32 -> B-fragment order:
// wp[((ct*64 + kt)*64 + l)*8 + j] = bf16( W[kt*32 + (l>>4)*8 + j][ct*16 + (l&15)] )
__global__ void pack_w(const float* __restrict__ W, u16* __restrict__ wp) {
  int tid = blockIdx.x * blockDim.x + threadIdx.x;   // 524288 threads
  if (tid >= (KK * GG / 16)) return;
  int j  = tid & 7;
  int g  = (tid >> 3) & 3;
  int kt = (tid >> 5) & 63;
  int ct = tid >> 11;                                // 0..255
  int k  = kt * 32 + g * 8 + j;
  const float* src = W + (size_t)k * GG + ct * 16;
  u16* dst = wp + (size_t)(ct * 64 + kt) * 512 + j;
  float4 v0 = *(const float4*)(src + 0);
  float4 v1 = *(const float4*)(src + 4);
  float4 v2 = *(const float4*)(src + 8);
  float4 v3 = *(const float4*)(src + 12);
  float vv[16] = {v0.x,v0.y,v0.z,v0.w, v1.x,v1.y,v1.z,v1.w,
                  v2.x,v2.y,v2.z,v2.w, v3.x,v3.y,v3.z,v3.w};
  #pragma unroll
  for (int c = 0; c < 16; ++c) dst[(size_t)(g * 16 + c) * 8] = f2bf(vv[c]);
}

// Pack x [N][T][F] fp32 -> A-fragment order per (t, rt):
// xp[(((t*4 + rt)*32 + kt)*64 + l)*8 + j] = bf16( x[16rt + (l&15)][t][kt*32 + (l>>4)*8 + j] )
__global__ void pack_x(const float* __restrict__ X, u16* __restrict__ xp) {
  int tid = blockIdx.x * blockDim.x + threadIdx.x;   // 2097152 threads
  if (tid >= (int)(NB * TT * FF / 8)) return;
  int l  = tid & 63;
  int kt = (tid >> 6) & 31;
  int rt = (tid >> 11) & 3;
  int t  = tid >> 13;                                // 0..255
  int n  = rt * 16 + (l & 15);
  int f  = kt * 32 + (l >> 4) * 8;
  const float* src = X + (size_t)n * TT * FF + (size_t)t * FF + f;
  float4 a = *(const float4*)(src);
  float4 b = *(const float4*)(src + 4);
  u16 tmp[8] = { f2bf(a.x), f2bf(a.y), f2bf(a.z), f2bf(a.w),
                 f2bf(b.x), f2bf(b.y), f2bf(b.z), f2bf(b.w) };
  *(uint4*)(xp + (size_t)((t * 4 + rt) * 32 + kt) * 512 + l * 8) = *(uint4*)tmp;
}

// zero barrier flags through the coherence point (ws is poisoned 0xAA; stale
// flags from a previous replay would open barriers spuriously)
__global__ void init_state(u32* __restrict__ flags) {
  int tid = threadIdx.x;
  #pragma unroll
  for (int i = 0; i < 4; ++i)
    __hip_atomic_store(&flags[i * 256 + tid], 0u, __ATOMIC_RELAXED,
                       __HIP_MEMORY_SCOPE_AGENT);
}

__launch_bounds__(1024, 1)  // 16 waves = 4 waves/SIMD
__global__ void lstm_main(const u16* __restrict__ wp, const u16* __restrict__ xp,
                          u32* __restrict__ hp32, const float* __restrict__ bias,
                          float* __restrict__ z, float* __restrict__ hout,
                          float* __restrict__ memout, u32* flags) {
  const int b   = blockIdx.x;        // 256 blocks, all co-resident
  const int cgi = b & 63;            // col-group: 16 h-cols
  const int rt  = b >> 6;            // row-tile: 16 batch rows -> barrier group
  const int tid = threadIdx.x;
  const int w16 = tid >> 6;          // wave 0..15
  const int g   = w16 & 3;           // gate index
  const int s   = w16 >> 2;          // K-quarter group
  const int l   = tid & 63;
  const int ct  = g * 64 + cgi;      // global col-tile 0..255

  const u16* bp = wp + (size_t)ct * 32768 + l * 8;   // 64 kt * 512 per col-tile
  const float bv = (s == 0) ? bias[ct * 16 + (l & 15)] : 0.f;
  u32* gf = flags + rt * 256;        // this rt-group's 64 flags, stride 4 u32

  __shared__ __align__(16) u16 whl[57344]; // 112 KB: W_h kt 4..31 x 4 gates (LDS-resident)
  __shared__ u32   hs32[8192];       // 32 KB staged h fragments (this rt group)
  __shared__ float gl[4][4][16][16]; // partial gate tiles [s-group][gate]
  // LDS total: 112 + 32 + 16 = 160 KiB exactly (1 block/CU)

  // ---- one-time prefill: W_h kt 4..31 of all 4 gates into LDS ----
  // frag f = g*28 + (kt-4); byte = f*1024 + lane*16; 7 x 16 KB = 114688 B exact
  #pragma unroll
  for (int j = 0; j < 7; ++j) {
    int byte = tid * 16 + j * 16384;
    int f    = byte >> 10;                   // 0..111
    int ll   = (byte & 1023) >> 4;           // lane 0..63
    int gg   = f / 28;
    int kt   = f % 28 + 4;                   // 4..31
    const u16* src = wp + (size_t)(gg * 64 + cgi) * 32768
                        + (size_t)(32 + kt) * 512 + ll * 8;
    *(uint4*)((char*)whl + byte) = *(const uint4*)src;
  }
  __syncthreads();

  const int er  = tid >> 4;          // 0..15 epilogue row   (valid for tid<256)
  const int ec  = tid & 15;          // 0..15 epilogue col
  const int m   = rt * 16 + er;      // batch row
  const int col = cgi * 16 + ec;     // col within gate [0,1024)
  // hp u32 slot for the (even) col pair this thread's pair-store covers
  const int col0 = col & ~1;
  const int kt2  = col0 >> 5;
  const int g2   = (col0 >> 3) & 3;
  const int l2   = er | (g2 << 4);
  const int cbase = kt2 * 256 + l2 * 4 + ((col0 & 7) >> 1);  // u32 units

  const u16* bx = bp + (size_t)(s * 8) * 512;   // this wave's W_x quarter

  float memv = 0.0f;                 // cell state (tid<256 only)

  // ---- prologue: cx = bias + x(0) @ W_x (software pipeline primer) ----
  f32x4 cx0 = {bv, bv, bv, bv};
  f32x4 cx1 = {0.f, 0.f, 0.f, 0.f};
  {
    const u16* ax = xp + (size_t)((0 * 4 + rt) * 32 + s * 8) * 512 + l * 8;
    #pragma unroll
    for (int kt = 0; kt < 8; kt += 2) {
      bf16x8 a0 = *(const bf16x8*)(ax + (size_t)kt * 512);
      bf16x8 b0 = *(const bf16x8*)(bx + (size_t)kt * 512);
      bf16x8 a1 = *(const bf16x8*)(ax + (size_t)(kt + 1) * 512);
      bf16x8 b1 = *(const bf16x8*)(bx + (size_t)(kt + 1) * 512);
      cx0 = __builtin_amdgcn_mfma_f32_16x16x32_bf16(a0, b0, cx0, 0, 0, 0);
      cx1 = __builtin_amdgcn_mfma_f32_16x16x32_bf16(a1, b1, cx1, 0, 0, 0);
    }
  }

  for (int t = 0; t < TT; ++t) {
    const int p = t & 1;             // h(t) lives in buffer p (written last step)

    // ---- 1) poll + ISSUE h-copy loads (oldest in vmcnt order) ----
    u32 tmpv[8];
    if (t != 0) {
      const u32 tgt = (u32)t;
      const int fc  = w16 * 4 + (l & 3);     // per-wave quadrant flag
      for (;;) {
        u32 v = __hip_atomic_load(&gf[fc * 4], __ATOMIC_RELAXED,
                                  __HIP_MEMORY_SCOPE_AGENT);
        if (fc == cgi) v = tgt;              // own arrival known locally
        if (!__any((int)(v < tgt))) break;
        __builtin_amdgcn_s_sleep(1);
      }
      // compiler fence: copy loads may not hoist above the poll
      asm volatile("" ::: "memory");
      const u32* hsrc = hp32 + (size_t)(p * 4 + rt) * 8192 + w16 * 512;
      #pragma unroll
      for (int i = 0; i < 8; ++i)
        tmpv[i] = __hip_atomic_load(hsrc + i * 64 + l, __ATOMIC_RELAXED,
                                    __HIP_MEMORY_SCOPE_AGENT);
      // compiler fence: copy loads may not sink below the x-GEMM
      asm volatile("" ::: "memory");
    }

    // ---- 2) x-GEMM(t+1) into nx: fills the h-copy fabric round-trip ----
    f32x4 nx0 = {bv, bv, bv, bv};
    f32x4 nx1 = {0.f, 0.f, 0.f, 0.f};
    if (t < TT - 1) {
      const u16* axn = xp + (size_t)(((t + 1) * 4 + rt) * 32 + s * 8) * 512 + l * 8;
      #pragma unroll
      for (int kt = 0; kt < 8; kt += 2) {
        bf16x8 a0 = *(const bf16x8*)(axn + (size_t)kt * 512);
        bf16x8 b0 = *(const bf16x8*)(bx + (size_t)kt * 512);
        bf16x8 a1 = *(const bf16x8*)(axn + (size_t)(kt + 1) * 512);
        bf16x8 b1 = *(const bf16x8*)(bx + (size_t)(kt + 1) * 512);
        nx0 = __builtin_amdgcn_mfma_f32_16x16x32_bf16(a0, b0, nx0, 0, 0, 0);
        nx1 = __builtin_amdgcn_mfma_f32_16x16x32_bf16(a1, b1, nx1, 0, 0, 0);
      }
    }

    if (t != 0) {
      // ---- 3) land the h-copy in LDS (waits only on the older copy loads) ----
      #pragma unroll
      for (int i = 0; i < 8; ++i)
        hs32[w16 * 512 + i * 64 + l] = tmpv[i];
      __syncthreads();               // barrier A: hs32 complete

      // ---- 4) h-GEMM into cx (same accumulation order as R18/R19) ----
      const char* hb = (const char*)hs32;
      {
        bf16x8 aL = *(const bf16x8*)(hb + (size_t)s * 1024 + l * 16);
        bf16x8 bL = *(const bf16x8*)(bp + (size_t)(32 + s) * 512);
        cx0 = __builtin_amdgcn_mfma_f32_16x16x32_bf16(aL, bL, cx0, 0, 0, 0);
      }
      const char* hb2 = hb + (size_t)(4 + 7 * s) * 1024 + l * 16;
      const u16*  bh  = whl + (size_t)(g * 28 + 7 * s) * 512 + l * 8;
      #pragma unroll
      for (int kt = 0; kt < 7; ++kt) {
        bf16x8 a0 = *(const bf16x8*)(hb2 + (size_t)kt * 1024);
        bf16x8 b0 = *(const bf16x8*)(bh + (size_t)kt * 512);
        if (kt & 1) cx0 = __builtin_amdgcn_mfma_f32_16x16x32_bf16(a0, b0, cx0, 0, 0, 0);
        else        cx1 = __builtin_amdgcn_mfma_f32_16x16x32_bf16(a0, b0, cx1, 0, 0, 0);
      }
    }

    // C-layout: col = l&15, row = (l>>4)*4 + r  (HW-verified)
    #pragma unroll
    for (int r = 0; r < 4; ++r)
      gl[s][g][(l >> 4) * 4 + r][l & 15] = cx0[r] + cx1[r];
    __syncthreads();                 // barrier B: gl ready

    float h;
    if (tid < 256) {
      // gate combine: sum the four s-group partials per gate
      float ai = (gl[0][0][er][ec] + gl[1][0][er][ec]) +
                 (gl[2][0][er][ec] + gl[3][0][er][ec]);
      float af = (gl[0][1][er][ec] + gl[1][1][er][ec]) +
                 (gl[2][1][er][ec] + gl[3][1][er][ec]);
      float ao = (gl[0][2][er][ec] + gl[1][2][er][ec]) +
                 (gl[2][2][er][ec] + gl[3][2][er][ec]);
      float ag = (gl[0][3][er][ec] + gl[1][3][er][ec]) +
                 (gl[2][3][er][ec] + gl[3][3][er][ec]);
      float si = 1.f / (1.f + __expf(-ai));
      float sf = 1.f / (1.f + __expf(-af));
      float so = 1.f / (1.f + __expf(-ao));
      float tg = 1.f - 2.f / (__expf(2.f * ag) + 1.f);   // safe tanh
      memv = sf * memv + si * tg;
      float th = 1.f - 2.f / (__expf(2.f * memv) + 1.f); // safe tanh
      h = so * th;

      // publish h as bf16 pairs through the coherence point (write-through)
      float hn = __shfl_xor(h, 1);   // partner col's h
      if ((ec & 1) == 0) {
        u32 pair = (u32)f2bf(h) | ((u32)f2bf(hn) << 16);
        __hip_atomic_store(&hp32[(size_t)((p ^ 1) * 4 + rt) * 8192 + cbase], pair,
                           __ATOMIC_RELAXED, __HIP_MEMORY_SCOPE_AGENT);
      }
    }

    if (t < TT - 1) {
      // PRODUCER DRAIN (the R20/R21 race): __syncthreads is only a
      // workgroup-scope fence — the compiler may legally sink the relaxed hp
      // store past it and past the flag store. Force every wave's publish to
      // COMPLETE at the coherence point before it reaches barrier C.
      asm volatile("s_waitcnt vmcnt(0)" ::: "memory");
      __syncthreads();               // barrier C
      asm volatile("" ::: "memory"); // flag store may not hoist above barrier C
      if (tid == 0)
        __hip_atomic_store(&gf[cgi * 4], (u32)(t + 1), __ATOMIC_RELAXED,
                           __HIP_MEMORY_SCOPE_AGENT);
    }

    if (tid < 256) {
      // z-store AFTER the flag publish: not on anyone's critical path
      z[((size_t)m * TT + t) * HH + col] = h;
      if (t == TT - 1) hout[(size_t)m * HH + col] = h;
    }

    // rotate the software pipeline
    cx0 = nx0;
    cx1 = nx1;
  }
  if (tid < 256) memout[(size_t)m * HH + col] = memv;
}

extern "C" void kernel_launch(void* const* d_in, const int* in_sizes, int n_in,
                              void* d_out, int out_size, void* d_ws, size_t ws_size,
                              hipStream_t stream) {
  const float* x    = (const float*)d_in[0];
  const float* W    = (const float*)d_in[1];
  const float* bias = (const float*)d_in[2];

  float* z      = (float*)d_out;
  float* hout   = z + (size_t)NB * TT * HH;
  float* memout = hout + (size_t)NB * HH;

  u16* wp = (u16*)d_ws;
  u16* xp = wp + WPACK_SZ;
  u16* hp = xp + XPACK_SZ;
  u32* flags = (u32*)(hp + HPACK_SZ);

  hipLaunchKernelGGL(pack_w, dim3(2048), dim3(256), 0, stream, W, wp);
  hipLaunchKernelGGL(pack_x, dim3(8192), dim3(256), 0, stream, x, xp);
  hipLaunchKernelGGL(init_state, dim3(1), dim3(256), 0, stream, flags);

  hipLaunchKernelGGL(lstm_main, dim3(NBLK), dim3(1024), 0, stream,
                     wp, xp, (u32*)hp, bias, z, hout, memout, flags);
}

// Round 23
// 781.213 us; speedup vs baseline: 1.7387x; 1.7387x over previous
//
#include <hip/hip_runtime.h>

typedef unsigned short u16;
typedef unsigned int   u32;
typedef __attribute__((ext_vector_type(8))) short bf16x8;
typedef __attribute__((ext_vector_type(4))) float f32x4;

#define NB 64
#define TT 256
#define FF 1024
#define HH 1024
#define KK 2048
#define GG 4096
#define NBLK 256

// ws layout in u16 units
#define WPACK_SZ  (KK*GG)                    // 8388608 u16 = 16 MB
#define XPACK_SZ  ((size_t)NB*TT*FF)         // 16777216 u16 = 32 MB
#define HPACK_SZ  (2*4*32*64*8)              // 131072 u16 = 256 KB (double buffer)
#define FLAGS_SZ  (4*64*4)                   // u32: 4 rt-groups x 64 flags, 16B stride

__device__ __forceinline__ u16 f2bf(float f) {
  u32 u = __float_as_uint(f);
  u32 r = (u + 0x7FFFu + ((u >> 16) & 1u)) >> 16;
  return (u16)r;
}

// Pack W [K=2048][G=4096] fp32 -> B-fragment order:
// wp[((ct*64 + kt)*64 + l)*8 + j] = bf16( W[kt*32 + (l>>4)*8 + j][ct*16 + (l&15)] )
__global__ void pack_w(const float* __restrict__ W, u16* __restrict__ wp) {
  int tid = blockIdx.x * blockDim.x + threadIdx.x;   // 524288 threads
  if (tid >= (KK * GG / 16)) return;
  int j  = tid & 7;
  int g  = (tid >> 3) & 3;
  int kt = (tid >> 5) & 63;
  int ct = tid >> 11;                                // 0..255
  int k  = kt * 32 + g * 8 + j;
  const float* src = W + (size_t)k * GG + ct * 16;
  u16* dst = wp + (size_t)(ct * 64 + kt) * 512 + j;
  float4 v0 = *(const float4*)(src + 0);
  float4 v1 = *(const float4*)(src + 4);
  float4 v2 = *(const float4*)(src + 8);
  float4 v3 = *(const float4*)(src + 12);
  float vv[16] = {v0.x,v0.y,v0.z,v0.w, v1.x,v1.y,v1.z,v1.w,
                  v2.x,v2.y,v2.z,v2.w, v3.x,v3.y,v3.z,v3.w};
  #pragma unroll
  for (int c = 0; c < 16; ++c) dst[(size_t)(g * 16 + c) * 8] = f2bf(vv[c]);
}

// Pack x [N][T][F] fp32 -> A-fragment order per (t, rt):
// xp[(((t*4 + rt)*32 + kt)*64 + l)*8 + j] = bf16( x[16rt + (l&15)][t][kt*32 + (l>>4)*8 + j] )
__global__ void pack_x(const float* __restrict__ X, u16* __restrict__ xp) {
  int tid = blockIdx.x * blockDim.x + threadIdx.x;   // 2097152 threads
  if (tid >= (int)(NB * TT * FF / 8)) return;
  int l  = tid & 63;
  int kt = (tid >> 6) & 31;
  int rt = (tid >> 11) & 3;
  int t  = tid >> 13;                                // 0..255
  int n  = rt * 16 + (l & 15);
  int f  = kt * 32 + (l >> 4) * 8;
  const float* src = X + (size_t)n * TT * FF + (size_t)t * FF + f;
  float4 a = *(const float4*)(src);
  float4 b = *(const float4*)(src + 4);
  u16 tmp[8] = { f2bf(a.x), f2bf(a.y), f2bf(a.z), f2bf(a.w),
                 f2bf(b.x), f2bf(b.y), f2bf(b.z), f2bf(b.w) };
  *(uint4*)(xp + (size_t)((t * 4 + rt) * 32 + kt) * 512 + l * 8) = *(uint4*)tmp;
}

// zero barrier flags through the coherence point (ws is poisoned 0xAA; stale
// flags from a previous replay would open barriers spuriously)
__global__ void init_state(u32* __restrict__ flags) {
  int tid = threadIdx.x;
  #pragma unroll
  for (int i = 0; i < 4; ++i)
    __hip_atomic_store(&flags[i * 256 + tid], 0u, __ATOMIC_RELAXED,
                       __HIP_MEMORY_SCOPE_AGENT);
}

__launch_bounds__(1024, 1)  // 16 waves = 4 waves/SIMD
__global__ void lstm_main(const u16* __restrict__ wp, const u16* __restrict__ xp,
                          u32* __restrict__ hp32, const float* __restrict__ bias,
                          float* __restrict__ z, float* __restrict__ hout,
                          float* __restrict__ memout, u32* flags) {
  const int b   = blockIdx.x;        // 256 blocks, all co-resident
  const int cgi = b & 63;            // col-group: 16 h-cols
  const int rt  = b >> 6;            // row-tile: 16 batch rows -> barrier group
  const int tid = threadIdx.x;
  const int w16 = tid >> 6;          // wave 0..15
  const int g   = w16 & 3;           // gate index
  const int s   = w16 >> 2;          // K-quarter group
  const int l   = tid & 63;
  const int ct  = g * 64 + cgi;      // global col-tile 0..255

  const u16* bp = wp + (size_t)ct * 32768 + l * 8;   // 64 kt * 512 per col-tile
  const float bv = (s == 0) ? bias[ct * 16 + (l & 15)] : 0.f;
  u32* gf = flags + rt * 256;        // this rt-group's 64 flags, stride 4 u32

  __shared__ __align__(16) u16 whl[57344]; // 112 KB: W_h kt 4..31 x 4 gates (LDS-resident)
  __shared__ u32   hs32[8192];       // 32 KB staged h fragments (this rt group)
  __shared__ float gl[4][4][16][16]; // partial gate tiles [s-group][gate]
  // LDS total: 112 + 32 + 16 = 160 KiB exactly (1 block/CU)

  // ---- one-time prefill: W_h kt 4..31 of all 4 gates into LDS ----
  // frag f = g*28 + (kt-4); byte = f*1024 + lane*16; 7 x 16 KB = 114688 B exact
  #pragma unroll
  for (int j = 0; j < 7; ++j) {
    int byte = tid * 16 + j * 16384;
    int f    = byte >> 10;                   // 0..111
    int ll   = (byte & 1023) >> 4;           // lane 0..63
    int gg   = f / 28;
    int kt   = f % 28 + 4;                   // 4..31
    const u16* src = wp + (size_t)(gg * 64 + cgi) * 32768
                        + (size_t)(32 + kt) * 512 + ll * 8;
    *(uint4*)((char*)whl + byte) = *(const uint4*)src;
  }

  // ---- per-wave W slice in REGISTERS (36 VGPR/lane): this wave's 8 W_x
  // fragments + its 1 L2-resident W_h fragment. Step-invariant -> loaded once.
  // (R6/R9's failure was the 64-frag/256-VGPR version; 9 frags fits easily.)
  const u16* bx0 = bp + (size_t)(s * 8) * 512;
  bf16x8 wx[8];
  #pragma unroll
  for (int kt = 0; kt < 8; ++kt)
    wx[kt] = *(const bf16x8*)(bx0 + (size_t)kt * 512);
  bf16x8 whr = *(const bf16x8*)(bp + (size_t)(32 + s) * 512);
  __syncthreads();

  const int er  = tid >> 4;          // 0..15 epilogue row   (valid for tid<256)
  const int ec  = tid & 15;          // 0..15 epilogue col
  const int m   = rt * 16 + er;      // batch row
  const int col = cgi * 16 + ec;     // col within gate [0,1024)
  // hp u32 slot for the (even) col pair this thread's pair-store covers
  const int col0 = col & ~1;
  const int kt2  = col0 >> 5;
  const int g2   = (col0 >> 3) & 3;
  const int l2   = er | (g2 << 4);
  const int cbase = kt2 * 256 + l2 * 4 + ((col0 & 7) >> 1);  // u32 units

  float memv = 0.0f;                 // cell state (tid<256 only)

  for (int t = 0; t < TT; ++t) {
    const int p = t & 1;             // h(t) lives in buffer p (written last step)
    const u16* ax = xp + (size_t)((t * 4 + rt) * 32 + s * 8) * 512 + l * 8;

    // ---- x GEMM: 8 MFMAs, A from L2/L1, B from REGISTERS ----
    f32x4 acc0 = {bv, bv, bv, bv};
    f32x4 acc1 = {0.f, 0.f, 0.f, 0.f};
    #pragma unroll
    for (int kt = 0; kt < 8; kt += 2) {
      bf16x8 a0 = *(const bf16x8*)(ax + (size_t)kt * 512);
      bf16x8 a1 = *(const bf16x8*)(ax + (size_t)(kt + 1) * 512);
      acc0 = __builtin_amdgcn_mfma_f32_16x16x32_bf16(a0, wx[kt],     acc0, 0, 0, 0);
      acc1 = __builtin_amdgcn_mfma_f32_16x16x32_bf16(a1, wx[kt + 1], acc1, 0, 0, 0);
    }

    if (t != 0) {
      // ---- per-wave poll+copy: wave w owns hp words [w*512, w*512+512) =
      // producers cgi {4w..4w+3}. A straggler delays only its quadrant's 2 KB.
      const u32 tgt = (u32)t;
      const int fc  = w16 * 4 + (l & 3);     // flag this lane watches
      for (;;) {
        u32 v = __hip_atomic_load(&gf[fc * 4], __ATOMIC_RELAXED,
                                  __HIP_MEMORY_SCOPE_AGENT);
        if (fc == cgi) v = tgt;              // own arrival known locally
        if (!__any((int)(v < tgt))) break;
        __builtin_amdgcn_s_sleep(1);
      }
      const u32* hsrc = hp32 + (size_t)(p * 4 + rt) * 8192 + w16 * 512;
      u32 tmpv[8];
      #pragma unroll
      for (int i = 0; i < 8; ++i)
        tmpv[i] = __hip_atomic_load(hsrc + i * 64 + l, __ATOMIC_RELAXED,
                                    __HIP_MEMORY_SCOPE_AGENT);
      #pragma unroll
      for (int i = 0; i < 8; ++i)
        hs32[w16 * 512 + i * 64 + l] = tmpv[i];
      __syncthreads();               // barrier A: hs32 complete

      // ---- h GEMM: 8 MFMAs; A from LDS; B: 1 kt from regs + 7 kt from LDS ----
      const char* hb = (const char*)hs32;
      {
        bf16x8 aL = *(const bf16x8*)(hb + (size_t)s * 1024 + l * 16);
        acc0 = __builtin_amdgcn_mfma_f32_16x16x32_bf16(aL, whr, acc0, 0, 0, 0);
      }
      const char* hb2 = hb + (size_t)(4 + 7 * s) * 1024 + l * 16;
      const u16*  bh  = whl + (size_t)(g * 28 + 7 * s) * 512 + l * 8;
      #pragma unroll
      for (int kt = 0; kt < 7; ++kt) {
        bf16x8 a0 = *(const bf16x8*)(hb2 + (size_t)kt * 1024);
        bf16x8 b0 = *(const bf16x8*)(bh + (size_t)kt * 512);
        if (kt & 1) acc0 = __builtin_amdgcn_mfma_f32_16x16x32_bf16(a0, b0, acc0, 0, 0, 0);
        else        acc1 = __builtin_amdgcn_mfma_f32_16x16x32_bf16(a0, b0, acc1, 0, 0, 0);
      }
    }

    // C-layout: col = l&15, row = (l>>4)*4 + r  (HW-verified)
    #pragma unroll
    for (int r = 0; r < 4; ++r)
      gl[s][g][(l >> 4) * 4 + r][l & 15] = acc0[r] + acc1[r];
    __syncthreads();                 // barrier B: gl ready

    float h;
    if (tid < 256) {
      // gate combine: sum the four s-group partials per gate
      float ai = (gl[0][0][er][ec] + gl[1][0][er][ec]) +
                 (gl[2][0][er][ec] + gl[3][0][er][ec]);
      float af = (gl[0][1][er][ec] + gl[1][1][er][ec]) +
                 (gl[2][1][er][ec] + gl[3][1][er][ec]);
      float ao = (gl[0][2][er][ec] + gl[1][2][er][ec]) +
                 (gl[2][2][er][ec] + gl[3][2][er][ec]);
      float ag = (gl[0][3][er][ec] + gl[1][3][er][ec]) +
                 (gl[2][3][er][ec] + gl[3][3][er][ec]);
      float si = 1.f / (1.f + __expf(-ai));
      float sf = 1.f / (1.f + __expf(-af));
      float so = 1.f / (1.f + __expf(-ao));
      float tg = 1.f - 2.f / (__expf(2.f * ag) + 1.f);   // safe tanh
      memv = sf * memv + si * tg;
      float th = 1.f - 2.f / (__expf(2.f * memv) + 1.f); // safe tanh
      h = so * th;

      // publish h as bf16 pairs through the coherence point (write-through)
      float hn = __shfl_xor(h, 1);   // partner col's h
      if ((ec & 1) == 0) {
        u32 pair = (u32)f2bf(h) | ((u32)f2bf(hn) << 16);
        __hip_atomic_store(&hp32[(size_t)((p ^ 1) * 4 + rt) * 8192 + cbase], pair,
                           __ATOMIC_RELAXED, __HIP_MEMORY_SCOPE_AGENT);
      }
    }

    if (t < TT - 1) {
      // barrier C: drains vmcnt(0) -> hp at coherence point; also separates
      // this step's hs32/gl reads from next step's writes.
      __syncthreads();
      if (tid == 0)
        __hip_atomic_store(&gf[cgi * 4], (u32)(t + 1), __ATOMIC_RELAXED,
                           __HIP_MEMORY_SCOPE_AGENT);
    }

    if (tid < 256) {
      // z-store AFTER the flag publish: not on anyone's critical path
      z[((size_t)m * TT + t) * HH + col] = h;
      if (t == TT - 1) hout[(size_t)m * HH + col] = h;
    }
  }
  if (tid < 256) memout[(size_t)m * HH + col] = memv;
}

extern "C" void kernel_launch(void* const* d_in, const int* in_sizes, int n_in,
                              void* d_out, int out_size, void* d_ws, size_t ws_size,
                              hipStream_t stream) {
  const float* x    = (const float*)d_in[0];
  const float* W    = (const float*)d_in[1];
  const float* bias = (const float*)d_in[2];

  float* z      = (float*)d_out;
  float* hout   = z + (size_t)NB * TT * HH;
  float* memout = hout + (size_t)NB * HH;

  u16* wp = (u16*)d_ws;
  u16* xp = wp + WPACK_SZ;
  u16* hp = xp + XPACK_SZ;
  u32* flags = (u32*)(hp + HPACK_SZ);

  hipLaunchKernelGGL(pack_w, dim3(2048), dim3(256), 0, stream, W, wp);
  hipLaunchKernelGGL(pack_x, dim3(8192), dim3(256), 0, stream, x, xp);
  hipLaunchKernelGGL(init_state, dim3(1), dim3(256), 0, stream, flags);

  hipLaunchKernelGGL(lstm_main, dim3(NBLK), dim3(1024), 0, stream,
                     wp, xp, (u32*)hp, bias, z, hout, memout, flags);
}